// Round 3
// baseline (94.999 us; speedup 1.0000x reference)
//
#include <hip/hip_runtime.h>

// VQC 12-qubit statevector, batch=1024. 256 threads/block (4 waves), one batch
// element per block, NR=16 float2 regs/thread. Whole kernel in ONE layout:
//   Layout B: b11b10 = w (q0,q1), b9..b4 = lane (q2..q7), b3..b0 = reg (q8..q11)
//
// R2 post-mortem: 5 gather-exchanges + 15 lgkmcnt(0) drains queued on the shared
// LDS pipe (VALUBusy 27%, 3.9M bank-conflict cycles). This version makes LDS
// exchanges RARE: Y q8..q11 = reg gates; Y q2..q7 = __shfl_xor lane gates
// (ds_swizzle: no LDS memory, no barriers, conflict-free); Y q0,q1 = fused into
// the exchange gather (wave bits). Only 2 LDS-memory exchanges remain (the
// CNOT-chain permutations after layers 0 and 1): write 8B/amp + 4-gather read
// 32B/amp, XOR-swizzled to the bank floor. 5 barriers total. Layer-0 Y_q0,q1
// folded into the closed-form encoding; layer-2 Zs dropped (diagonal before
// |amp|^2); layer 2 has no CNOT -> no exchange at all.
//
// LDS: 32768 B exactly (redBuf aliased into bufc after last exchange).
// Swizzle key K(byte) = (((byte>>9)^(byte>>12))&7)<<4, applied identically on
// write and read (function of slot bits >=9 only -> b128 contiguity preserved).
// Gather reads: 64 distinct addrs, 8 lanes/bank-quad = dual-access floor.

#define PI_F 3.14159265358979323846f
#define NR 16

__device__ __forceinline__ float2 cmul(float2 a, float2 b) {
    return make_float2(a.x*b.x - a.y*b.y, a.x*b.y + a.y*b.x);
}
__device__ __forceinline__ float2 cmulc(float2 a, float2 b) {  // a * conj(b)
    return make_float2(a.x*b.x + a.y*b.y, a.y*b.x - a.x*b.y);
}

template<int RB>
__device__ __forceinline__ void ypow_reg(float2 (&a)[NR], float c, float s) {
    #pragma unroll
    for (int r0 = 0; r0 < NR; ++r0) {
        if ((r0 >> RB) & 1) continue;
        const int r1 = r0 | (1 << RB);
        float2 a0 = a[r0], a1 = a[r1];
        a[r0] = make_float2(c*a0.x - s*a1.x, c*a0.y - s*a1.y);
        a[r1] = make_float2(s*a0.x + c*a1.x, s*a0.y + c*a1.y);
    }
}

// Y on a LANE bit (xor mask M) via shfl: a' = c*a + (bit? +s : -s)*partner.
template<int M>
__device__ __forceinline__ void ypow_lane(float2 (&a)[NR], int lane, float c, float s) {
    const float k1 = (lane & M) ? s : -s;
    #pragma unroll
    for (int r = 0; r < NR; ++r) {
        float px = __shfl_xor(a[r].x, M, 64);
        float py = __shfl_xor(a[r].y, M, 64);
        a[r].x = c*a[r].x + k1*px;
        a[r].y = c*a[r].y + k1*py;
    }
}

__device__ __forceinline__ void ypowB(float2 (&a)[NR], const float* __restrict__ th) {
    // layout B reg bit 3..0 = b3..b0 = q8..q11
    { float s,c; __sincosf(0.5f*PI_F*th[16], &s,&c); ypow_reg<3>(a,c,s); }   // q8
    { float s,c; __sincosf(0.5f*PI_F*th[18], &s,&c); ypow_reg<2>(a,c,s); }   // q9
    { float s,c; __sincosf(0.5f*PI_F*th[20], &s,&c); ypow_reg<1>(a,c,s); }   // q10
    { float s,c; __sincosf(0.5f*PI_F*th[22], &s,&c); ypow_reg<0>(a,c,s); }   // q11
}

__device__ __forceinline__ void ypow_lanes(float2 (&a)[NR], int lane,
                                           const float* __restrict__ th) {
    // lane bit k <-> q(7-k): q2->xor32, q3->16, q4->8, q5->4, q6->2, q7->1
    { float s,c; __sincosf(0.5f*PI_F*th[4],  &s,&c); ypow_lane<32>(a,lane,c,s); }
    { float s,c; __sincosf(0.5f*PI_F*th[6],  &s,&c); ypow_lane<16>(a,lane,c,s); }
    { float s,c; __sincosf(0.5f*PI_F*th[8],  &s,&c); ypow_lane<8>(a,lane,c,s); }
    { float s,c; __sincosf(0.5f*PI_F*th[10], &s,&c); ypow_lane<4>(a,lane,c,s); }
    { float s,c; __sincosf(0.5f*PI_F*th[12], &s,&c); ypow_lane<2>(a,lane,c,s); }
    { float s,c; __sincosf(0.5f*PI_F*th[14], &s,&c); ypow_lane<1>(a,lane,c,s); }
}

// B->B exchange: CNOT-chain permutation (input x = y ^ (y>>1)) fused with the
// NEXT layer's Y_q0 (b11), Y_q1 (b10) as a 4-way cross-wave gather.
// Slot for input amp x: S = ((x9^u)<<9)|x[8:0], byte = S<<5 | u<<4 | v<<3,
// u = x10^x11 (= z10), v = x11 (= z11). Reader (output y): t = ylow^(ylow>>1)
// over ylow = y[9:0]; the 4 inputs sit contiguously at bytes t<<5 .. t<<5+31.
__device__ __forceinline__ void exchange_BB(float2 (&a)[NR], char* bufc,
                                            int w, int lane, bool preSync,
                                            float c0, float s0, float c1, float s1) {
    if (preSync) __syncthreads();    // previous exchange's reads done everywhere
    const int v_ = (w >> 1) & 1;
    const int u_ = v_ ^ (w & 1);
    const int s9 = ((lane >> 5) ^ u_) & 1;
    const int wbyte = (s9 << 14) | ((lane & 31) << 9) | (u_ << 4) | (v_ << 3);
    #pragma unroll
    for (int r = 0; r < NR; ++r) {   // amp x = w<<10 | lane<<4 | r
        const int byt = wbyte | (r << 5);
        const int key = (((byt >> 9) ^ (byt >> 12)) & 7) << 4;
        *(float2*)(bufc + (byt ^ key)) = a[r];
    }
    __syncthreads();
    const float ky00 = (w & 2) ? s0 : c0;     // Y0[y11, z11=0]
    const float ky01 = (w & 2) ? c0 : -s0;    // Y0[y11, z11=1]
    const float ky10 = (w & 1) ? s1 : c1;     // Y1[y10, z10=0]
    const float ky11 = (w & 1) ? c1 : -s1;    // Y1[y10, z10=1]
    const float k00 = ky10*ky00, k01 = ky10*ky01, k10 = ky11*ky00, k11 = ky11*ky01;
    #pragma unroll
    for (int r = 0; r < NR; ++r) {            // out y = w<<10 | lane<<4 | r
        const int ylow = (lane << 4) | r;
        const int t = ylow ^ (ylow >> 1);     // 10-bit Gray inverse
        const int base = t << 5;
        const int key = (((base >> 9) ^ (base >> 12)) & 7) << 4;
        float4 p01 = *(const float4*)(bufc + (base ^ key));         // (z10,z11)=00,01
        float4 p23 = *(const float4*)(bufc + ((base | 16) ^ key));  // (z10,z11)=10,11
        a[r] = make_float2(k00*p01.x + k01*p01.z + k10*p23.x + k11*p23.z,
                           k00*p01.y + k01*p01.w + k10*p23.y + k11*p23.w);
        if ((r & 3) == 3) asm volatile("" ::: "memory");  // cap in-flight loads
    }
}

// Fused Z for all 12 qubits (layout B), Gray-code running complex product.
__device__ __forceinline__ void fused_z_B(float2 (&a)[NR], int w, int lane,
                                          const float* __restrict__ th) {
    float alpha = ((w & 2) ? th[1] : 0.0f) + ((w & 1) ? th[3] : 0.0f);  // q0,q1
    #pragma unroll
    for (int k = 0; k < 6; ++k)               // lane bit k <-> q(7-k)
        alpha += ((lane >> k) & 1) ? th[2*(7-k)+1] : 0.0f;
    float2 zb; __sincosf(PI_F * alpha, &zb.y, &zb.x);
    float2 zq[4];
    #pragma unroll
    for (int j = 0; j < 4; ++j)               // reg bit j <-> q(11-j)
        __sincosf(PI_F * th[2*(11-j)+1], &zq[j].y, &zq[j].x);
    float2 cur = zb;
    a[0] = cmul(a[0], cur);
    #pragma unroll
    for (int k = 1; k < NR; ++k) {
        const int bit = __builtin_ctz(k);
        const int g = k ^ (k >> 1);
        cur = ((g >> bit) & 1) ? cmul(cur, zq[bit]) : cmulc(cur, zq[bit]);
        a[g] = cmul(a[g], cur);
    }
}

__global__ __launch_bounds__(256) void vqc_kernel(
    const float* __restrict__ inputs,   // [1024,12]
    const float* __restrict__ thetas,   // [72] = [3][12][2]
    float* __restrict__ out)            // [1024,12]
{
    __shared__ __align__(16) char bufc[32768];   // exchange buffer; reused as redBuf

    const int b = blockIdx.x;
    const int tid = threadIdx.x;
    const int w = tid >> 6;          // w1=b11(q0), w0=b10(q1)
    const int lane = tid & 63;
    const float* x = inputs + b * 12;

    float2 a[NR];

    // ---- Encoding (closed form, directly in layout B) with layer-0 Y_q0,q1.
    // amp = 2^-6 * F0(b11) * F1(b10) * cis(pi * sum_{q>=2 set} x_q)
    float phb = 0.0f;
    #pragma unroll
    for (int k = 0; k < 6; ++k)               // lane bit k <-> q(7-k)
        phb += ((lane >> k) & 1) ? x[7 - k] : 0.0f;
    float2 cisb; __sincosf(PI_F * phb, &cisb.y, &cisb.x);
    float2 E0; __sincosf(PI_F * x[0], &E0.y, &E0.x);
    float2 E1; __sincosf(PI_F * x[1], &E1.y, &E1.x);
    float sa, ca; __sincosf(0.5f * PI_F * thetas[0], &sa, &ca);
    float sb, cb; __sincosf(0.5f * PI_F * thetas[2], &sb, &cb);
    float2 F0 = (w & 2) ? make_float2(sa + ca*E0.x,  ca*E0.y)
                        : make_float2(ca - sa*E0.x, -sa*E0.y);
    float2 F1 = (w & 1) ? make_float2(sb + cb*E1.x,  cb*E1.y)
                        : make_float2(cb - sb*E1.x, -sb*E1.y);
    float2 g0 = cmul(cmul(F0, F1), cisb);
    g0.x *= 0.015625f; g0.y *= 0.015625f;
    float2 zr[4];
    #pragma unroll
    for (int j = 0; j < 4; ++j)               // reg bit j <-> q(11-j)
        __sincosf(PI_F * x[11 - j], &zr[j].y, &zr[j].x);
    {
        float2 cur = g0;
        a[0] = cur;
        #pragma unroll
        for (int k = 1; k < NR; ++k) {
            const int bit = __builtin_ctz(k);
            const int g = k ^ (k >> 1);
            cur = ((g >> bit) & 1) ? cmul(cur, zr[bit]) : cmulc(cur, zr[bit]);
            a[g] = cur;
        }
    }

    const float* th0 = thetas;
    const float* th1 = thetas + 24;
    const float* th2 = thetas + 48;

    // ----- layer 0 -----
    ypowB(a, th0);
    ypow_lanes(a, lane, th0);
    fused_z_B(a, w, lane, th0);
    { float s0,c0,s1,c1;
      __sincosf(0.5f*PI_F*th1[0], &s0,&c0);
      __sincosf(0.5f*PI_F*th1[2], &s1,&c1);
      exchange_BB(a, bufc, w, lane, false, c0,s0,c1,s1); }

    // ----- layer 1 -----
    ypowB(a, th1);
    ypow_lanes(a, lane, th1);
    fused_z_B(a, w, lane, th1);
    { float s0,c0,s1,c1;
      __sincosf(0.5f*PI_F*th2[0], &s0,&c0);
      __sincosf(0.5f*PI_F*th2[2], &s1,&c1);
      exchange_BB(a, bufc, w, lane, true, c0,s0,c1,s1); }

    // ----- layer 2 (no CNOT -> no exchange; Zs dropped) -----
    ypowB(a, th2);
    ypow_lanes(a, lane, th2);

    // ---- Readout in layout B: q0=w1, q1=w0, q2..q7=lane bits 5..0, q8..q11=reg
    float totalP = 0.0f;
    float D[4] = {0, 0, 0, 0};
    #pragma unroll
    for (int r = 0; r < NR; ++r) {
        const float p = a[r].x * a[r].x + a[r].y * a[r].y;
        totalP += p;
        #pragma unroll
        for (int j = 0; j < 4; ++j)
            D[j] += ((r >> j) & 1) ? -p : p;
    }
    float* redBuf = (float*)bufc;             // bufc free after last exchange
    __syncthreads();                          // all exchange reads complete
    #pragma unroll
    for (int q = 0; q < 12; ++q) {
        float v;
        if (q == 0)      v = (w & 2) ? -totalP : totalP;
        else if (q == 1) v = (w & 1) ? -totalP : totalP;
        else if (q <= 7) v = ((lane >> (7 - q)) & 1) ? -totalP : totalP;
        else             v = D[11 - q];
        #pragma unroll
        for (int off = 32; off >= 1; off >>= 1)
            v += __shfl_xor(v, off, 64);
        if (lane == 0) redBuf[w * 12 + q] = v;
    }
    __syncthreads();
    if (tid < 12)
        out[b * 12 + tid] = redBuf[tid] + redBuf[12 + tid]
                          + redBuf[24 + tid] + redBuf[36 + tid];
}

extern "C" void kernel_launch(void* const* d_in, const int* in_sizes, int n_in,
                              void* d_out, int out_size, void* d_ws, size_t ws_size,
                              hipStream_t stream) {
    const float* inputs = (const float*)d_in[0];   // [1024,12] f32
    const float* thetas = (const float*)d_in[1];   // [72] f32
    float* out = (float*)d_out;                    // [1024,12] f32
    vqc_kernel<<<dim3(1024), dim3(256), 0, stream>>>(inputs, thetas, out);
}

// Round 4
// 81.943 us; speedup vs baseline: 1.1593x; 1.1593x over previous
//
#include <hip/hip_runtime.h>

// VQC 12-qubit statevector, batch=1024. 256 threads/block (4 waves), one batch
// element per block, NR=16 v2f regs/thread. Single layout:
//   Layout B: b11b10 = w (q0,q1), b9..b4 = lane (q2..q7), b3..b0 = reg (q8..q11)
//
// R3 post-mortem: latency-bound (VALUBusy 36%, DS ~23%, neither saturated).
// 576 ds_bpermute (__shfl_xor) in 18 serial gate stages dominated exposed
// latency. R4: (1) cross-lane primitives by mask: xor1/2 -> DPP quad_perm
// (pure VALU), xor4/8/16 -> ds_swizzle imm (no addr VALU), xor32 -> shfl;
// (2) amplitudes as ext_vector float2 so gate/Z math can emit v_pk_fma_f32.
// Exchange structure (2 LDS CNOT+Y_q0q1 exchanges, 5 barriers) unchanged.

#define PI_F 3.14159265358979323846f
#define NR 16

typedef __attribute__((ext_vector_type(2))) float v2f;
typedef __attribute__((ext_vector_type(4))) float v4f;

__device__ __forceinline__ v2f mkv(float x, float y) { v2f r; r.x = x; r.y = y; return r; }

__device__ __forceinline__ v2f cmul(v2f a, v2f b) {   // complex a*b
    return a.x * b + a.y * mkv(-b.y, b.x);
}
__device__ __forceinline__ v2f cmulc(v2f a, v2f b) {  // a * conj(b)
    return a.x * mkv(b.x, -b.y) + a.y * mkv(b.y, b.x);
}

// ---- cross-lane xor primitives ----
template<int M>
__device__ __forceinline__ float lane_xor_f(float v) {
    if constexpr (M == 1) {        // quad_perm [1,0,3,2]
        return __int_as_float(__builtin_amdgcn_update_dpp(
            0, __float_as_int(v), 0xB1, 0xF, 0xF, false));
    } else if constexpr (M == 2) { // quad_perm [2,3,0,1]
        return __int_as_float(__builtin_amdgcn_update_dpp(
            0, __float_as_int(v), 0x4E, 0xF, 0xF, false));
    } else if constexpr (M == 4) {
        return __int_as_float(__builtin_amdgcn_ds_swizzle(__float_as_int(v), 0x101F));
    } else if constexpr (M == 8) {
        return __int_as_float(__builtin_amdgcn_ds_swizzle(__float_as_int(v), 0x201F));
    } else if constexpr (M == 16) {
        return __int_as_float(__builtin_amdgcn_ds_swizzle(__float_as_int(v), 0x401F));
    } else {                       // M == 32: cross-half
        return __shfl_xor(v, 32, 64);
    }
}
template<int M>
__device__ __forceinline__ v2f lane_xor_v(v2f v) {
    return mkv(lane_xor_f<M>(v.x), lane_xor_f<M>(v.y));
}

template<int RB>
__device__ __forceinline__ void ypow_reg(v2f (&a)[NR], float c, float s) {
    #pragma unroll
    for (int r0 = 0; r0 < NR; ++r0) {
        if ((r0 >> RB) & 1) continue;
        const int r1 = r0 | (1 << RB);
        v2f a0 = a[r0], a1 = a[r1];
        a[r0] = c * a0 - s * a1;
        a[r1] = s * a0 + c * a1;
    }
}

// Y on a LANE bit (xor mask M): a' = c*a + (bit? +s : -s)*partner.
template<int M>
__device__ __forceinline__ void ypow_lane(v2f (&a)[NR], int lane, float c, float s) {
    const float k1 = (lane & M) ? s : -s;
    #pragma unroll
    for (int r = 0; r < NR; ++r) {
        v2f p = lane_xor_v<M>(a[r]);
        a[r] = c * a[r] + k1 * p;
    }
}

__device__ __forceinline__ void ypowB(v2f (&a)[NR], const float* __restrict__ th) {
    // layout B reg bit 3..0 = b3..b0 = q8..q11
    { float s,c; __sincosf(0.5f*PI_F*th[16], &s,&c); ypow_reg<3>(a,c,s); }   // q8
    { float s,c; __sincosf(0.5f*PI_F*th[18], &s,&c); ypow_reg<2>(a,c,s); }   // q9
    { float s,c; __sincosf(0.5f*PI_F*th[20], &s,&c); ypow_reg<1>(a,c,s); }   // q10
    { float s,c; __sincosf(0.5f*PI_F*th[22], &s,&c); ypow_reg<0>(a,c,s); }   // q11
}

__device__ __forceinline__ void ypow_lanes(v2f (&a)[NR], int lane,
                                           const float* __restrict__ th) {
    // lane bit k <-> q(7-k): q2->xor32, q3->16, q4->8, q5->4, q6->2, q7->1
    { float s,c; __sincosf(0.5f*PI_F*th[4],  &s,&c); ypow_lane<32>(a,lane,c,s); }
    { float s,c; __sincosf(0.5f*PI_F*th[6],  &s,&c); ypow_lane<16>(a,lane,c,s); }
    { float s,c; __sincosf(0.5f*PI_F*th[8],  &s,&c); ypow_lane<8>(a,lane,c,s); }
    { float s,c; __sincosf(0.5f*PI_F*th[10], &s,&c); ypow_lane<4>(a,lane,c,s); }
    { float s,c; __sincosf(0.5f*PI_F*th[12], &s,&c); ypow_lane<2>(a,lane,c,s); }
    { float s,c; __sincosf(0.5f*PI_F*th[14], &s,&c); ypow_lane<1>(a,lane,c,s); }
}

// B->B exchange: CNOT-chain permutation (input x = y ^ (y>>1)) fused with the
// NEXT layer's Y_q0 (b11), Y_q1 (b10) as a 4-way cross-wave gather.
// Slot for input amp x: S = ((x9^u)<<9)|x[8:0], byte = S<<5 | u<<4 | v<<3,
// u = x10^x11 (= z10), v = x11 (= z11). Reader (output y): t = ylow^(ylow>>1)
// over ylow = y[9:0]; the 4 inputs sit contiguously at bytes t<<5 .. t<<5+31.
// Swizzle key K(byte) = (((byte>>9)^(byte>>12))&7)<<4, same fn on write & read.
__device__ __forceinline__ void exchange_BB(v2f (&a)[NR], char* bufc,
                                            int w, int lane, bool preSync,
                                            float c0, float s0, float c1, float s1) {
    if (preSync) __syncthreads();    // previous exchange's reads done everywhere
    const int v_ = (w >> 1) & 1;
    const int u_ = v_ ^ (w & 1);
    const int s9 = ((lane >> 5) ^ u_) & 1;
    const int wbyte = (s9 << 14) | ((lane & 31) << 9) | (u_ << 4) | (v_ << 3);
    #pragma unroll
    for (int r = 0; r < NR; ++r) {   // amp x = w<<10 | lane<<4 | r
        const int byt = wbyte | (r << 5);
        const int key = (((byt >> 9) ^ (byt >> 12)) & 7) << 4;
        *(v2f*)(bufc + (byt ^ key)) = a[r];
    }
    __syncthreads();
    const float ky00 = (w & 2) ? s0 : c0;     // Y0[y11, z11=0]
    const float ky01 = (w & 2) ? c0 : -s0;    // Y0[y11, z11=1]
    const float ky10 = (w & 1) ? s1 : c1;     // Y1[y10, z10=0]
    const float ky11 = (w & 1) ? c1 : -s1;    // Y1[y10, z10=1]
    const float k00 = ky10*ky00, k01 = ky10*ky01, k10 = ky11*ky00, k11 = ky11*ky01;
    #pragma unroll
    for (int r = 0; r < NR; ++r) {            // out y = w<<10 | lane<<4 | r
        const int ylow = (lane << 4) | r;
        const int t = ylow ^ (ylow >> 1);     // 10-bit Gray inverse
        const int base = t << 5;
        const int key = (((base >> 9) ^ (base >> 12)) & 7) << 4;
        v4f p01 = *(const v4f*)(bufc + (base ^ key));         // (z10,z11)=00,01
        v4f p23 = *(const v4f*)(bufc + ((base | 16) ^ key));  // (z10,z11)=10,11
        a[r] = k00 * p01.xy + k01 * p01.zw + k10 * p23.xy + k11 * p23.zw;
        if ((r & 7) == 7) asm volatile("" ::: "memory");  // cap in-flight loads
    }
}

// Fused Z for all 12 qubits (layout B), Gray-code running complex product.
__device__ __forceinline__ void fused_z_B(v2f (&a)[NR], int w, int lane,
                                          const float* __restrict__ th) {
    float alpha = ((w & 2) ? th[1] : 0.0f) + ((w & 1) ? th[3] : 0.0f);  // q0,q1
    #pragma unroll
    for (int k = 0; k < 6; ++k)               // lane bit k <-> q(7-k)
        alpha += ((lane >> k) & 1) ? th[2*(7-k)+1] : 0.0f;
    float zbs, zbc; __sincosf(PI_F * alpha, &zbs, &zbc);
    v2f zq[4];
    #pragma unroll
    for (int j = 0; j < 4; ++j) {             // reg bit j <-> q(11-j)
        float ss, cc; __sincosf(PI_F * th[2*(11-j)+1], &ss, &cc);
        zq[j] = mkv(cc, ss);
    }
    v2f cur = mkv(zbc, zbs);
    a[0] = cmul(a[0], cur);
    #pragma unroll
    for (int k = 1; k < NR; ++k) {
        const int bit = __builtin_ctz(k);
        const int g = k ^ (k >> 1);
        cur = ((g >> bit) & 1) ? cmul(cur, zq[bit]) : cmulc(cur, zq[bit]);
        a[g] = cmul(a[g], cur);
    }
}

__global__ __launch_bounds__(256) void vqc_kernel(
    const float* __restrict__ inputs,   // [1024,12]
    const float* __restrict__ thetas,   // [72] = [3][12][2]
    float* __restrict__ out)            // [1024,12]
{
    __shared__ __align__(16) char bufc[32768];   // exchange buffer; reused as redBuf

    const int b = blockIdx.x;
    const int tid = threadIdx.x;
    const int w = tid >> 6;          // w1=b11(q0), w0=b10(q1)
    const int lane = tid & 63;
    const float* x = inputs + b * 12;

    v2f a[NR];

    // ---- Encoding (closed form, directly in layout B) with layer-0 Y_q0,q1.
    // amp = 2^-6 * F0(b11) * F1(b10) * cis(pi * sum_{q>=2 set} x_q)
    float phb = 0.0f;
    #pragma unroll
    for (int k = 0; k < 6; ++k)               // lane bit k <-> q(7-k)
        phb += ((lane >> k) & 1) ? x[7 - k] : 0.0f;
    float cbs, cbc; __sincosf(PI_F * phb, &cbs, &cbc);
    v2f cisb = mkv(cbc, cbs);
    float e0s, e0c; __sincosf(PI_F * x[0], &e0s, &e0c);
    float e1s, e1c; __sincosf(PI_F * x[1], &e1s, &e1c);
    float sa, ca; __sincosf(0.5f * PI_F * thetas[0], &sa, &ca);
    float sb, cb; __sincosf(0.5f * PI_F * thetas[2], &sb, &cb);
    v2f F0 = (w & 2) ? mkv(sa + ca*e0c,  ca*e0s)
                     : mkv(ca - sa*e0c, -sa*e0s);
    v2f F1 = (w & 1) ? mkv(sb + cb*e1c,  cb*e1s)
                     : mkv(cb - sb*e1c, -sb*e1s);
    v2f g0 = cmul(cmul(F0, F1), cisb);
    g0 = g0 * 0.015625f;
    v2f zr[4];
    #pragma unroll
    for (int j = 0; j < 4; ++j) {             // reg bit j <-> q(11-j)
        float ss, cc; __sincosf(PI_F * x[11 - j], &ss, &cc);
        zr[j] = mkv(cc, ss);
    }
    {
        v2f cur = g0;
        a[0] = cur;
        #pragma unroll
        for (int k = 1; k < NR; ++k) {
            const int bit = __builtin_ctz(k);
            const int g = k ^ (k >> 1);
            cur = ((g >> bit) & 1) ? cmul(cur, zr[bit]) : cmulc(cur, zr[bit]);
            a[g] = cur;
        }
    }

    const float* th0 = thetas;
    const float* th1 = thetas + 24;
    const float* th2 = thetas + 48;

    // ----- layer 0 -----
    ypowB(a, th0);
    ypow_lanes(a, lane, th0);
    fused_z_B(a, w, lane, th0);
    { float s0,c0,s1,c1;
      __sincosf(0.5f*PI_F*th1[0], &s0,&c0);
      __sincosf(0.5f*PI_F*th1[2], &s1,&c1);
      exchange_BB(a, bufc, w, lane, false, c0,s0,c1,s1); }

    // ----- layer 1 -----
    ypowB(a, th1);
    ypow_lanes(a, lane, th1);
    fused_z_B(a, w, lane, th1);
    { float s0,c0,s1,c1;
      __sincosf(0.5f*PI_F*th2[0], &s0,&c0);
      __sincosf(0.5f*PI_F*th2[2], &s1,&c1);
      exchange_BB(a, bufc, w, lane, true, c0,s0,c1,s1); }

    // ----- layer 2 (no CNOT -> no exchange; Zs dropped) -----
    ypowB(a, th2);
    ypow_lanes(a, lane, th2);

    // ---- Readout in layout B: q0=w1, q1=w0, q2..q7=lane bits 5..0, q8..q11=reg
    float totalP = 0.0f;
    float D[4] = {0, 0, 0, 0};
    #pragma unroll
    for (int r = 0; r < NR; ++r) {
        const float p = a[r].x * a[r].x + a[r].y * a[r].y;
        totalP += p;
        #pragma unroll
        for (int j = 0; j < 4; ++j)
            D[j] += ((r >> j) & 1) ? -p : p;
    }
    float* redBuf = (float*)bufc;             // bufc free after last exchange
    __syncthreads();                          // all exchange reads complete
    #pragma unroll
    for (int q = 0; q < 12; ++q) {
        float v;
        if (q == 0)      v = (w & 2) ? -totalP : totalP;
        else if (q == 1) v = (w & 1) ? -totalP : totalP;
        else if (q <= 7) v = ((lane >> (7 - q)) & 1) ? -totalP : totalP;
        else             v = D[11 - q];
        v += lane_xor_f<32>(v);
        v += lane_xor_f<16>(v);
        v += lane_xor_f<8>(v);
        v += lane_xor_f<4>(v);
        v += lane_xor_f<2>(v);
        v += lane_xor_f<1>(v);
        if (lane == 0) redBuf[w * 12 + q] = v;
    }
    __syncthreads();
    if (tid < 12)
        out[b * 12 + tid] = redBuf[tid] + redBuf[12 + tid]
                          + redBuf[24 + tid] + redBuf[36 + tid];
}

extern "C" void kernel_launch(void* const* d_in, const int* in_sizes, int n_in,
                              void* d_out, int out_size, void* d_ws, size_t ws_size,
                              hipStream_t stream) {
    const float* inputs = (const float*)d_in[0];   // [1024,12] f32
    const float* thetas = (const float*)d_in[1];   // [72] f32
    float* out = (float*)d_out;                    // [1024,12] f32
    vqc_kernel<<<dim3(1024), dim3(256), 0, stream>>>(inputs, thetas, out);
}